// Round 16
// baseline (719.083 us; speedup 1.0000x reference)
//
#include <hip/hip_runtime.h>
#include <math.h>

#define T_STEPS 8
#define HW 4096
#define XSTR 192                    // XT channel stride (fixed, max cin)
#define FR_ROW 4352                 // convx u16 per (img,row)

typedef unsigned short u16;
typedef __attribute__((ext_vector_type(8))) short short8;
typedef __attribute__((ext_vector_type(4))) short short4v;
typedef __attribute__((ext_vector_type(4))) float f32x4;

__device__ __forceinline__ u16 f2bf(float f) {
    unsigned u = __builtin_bit_cast(unsigned, f);
    u += 0x7fffu + ((u >> 16) & 1u);
    return (u16)(u >> 16);
}
__device__ __forceinline__ float bf2f(u16 h) {
    unsigned u = ((unsigned)h) << 16;
    return __builtin_bit_cast(float, u);
}
__device__ __forceinline__ float ftanh(float x) {
    float e = __expf(2.f * x);
    return 1.f - 2.f * __builtin_amdgcn_rcpf(e + 1.f);
}
__device__ __forceinline__ float fsigm(float x) {
    return __builtin_amdgcn_rcpf(1.f + __expf(-x));
}

// ---------------------------------------------------------------------------
// l0 only: fp32 x [img][32][64][64] -> bf16 XT[img][66][66][192] ch 0..31
// ---------------------------------------------------------------------------
__global__ __launch_bounds__(256) void transpose_halo(
    const float* __restrict__ src, u16* __restrict__ XT, int src_ctot)
{
    __shared__ float tile[32][257];
    const int img = blockIdx.z;
    const int px0 = blockIdx.x * 256;
    const float* s = src + (size_t)img * src_ctot * HW + px0;
    #pragma unroll
    for (int c = 0; c < 32; ++c)
        tile[c][threadIdx.x] = s[(size_t)c * HW + threadIdx.x];
    __syncthreads();
    const int c = threadIdx.x & 31, pb = threadIdx.x >> 5;
    const int r0 = px0 >> 6;
    for (int p = pb; p < 256; p += 8) {
        int row = r0 + (p >> 6), col = p & 63;
        XT[((size_t)img * 4356 + (row + 1) * 66 + col + 1) * XSTR + c] = f2bf(tile[c][p]);
    }
}

// ---------------------------------------------------------------------------
// Zero only XT's halo border cells (260 px/img, all 192 ch)
// ---------------------------------------------------------------------------
__global__ __launch_bounds__(256) void zero_border(u16* __restrict__ XT)
{
    int idx = blockIdx.x * 256 + threadIdx.x;      // 32*260*24 = 199,680
    if (idx >= 199680) return;
    int c8 = idx % 24;
    int rest = idx / 24;
    int bp = rest % 260;
    int img = rest / 260;
    int row, col;
    if (bp < 66)       { row = 0;  col = bp; }
    else if (bp < 132) { row = 65; col = bp - 66; }
    else if (bp < 196) { col = 0;  row = 1 + bp - 132; }
    else               { col = 65; row = 1 + bp - 196; }
    short8 zz = {0, 0, 0, 0, 0, 0, 0, 0};
    *(short8*)(XT + ((size_t)img * 4356 + row * 66 + col) * XSTR + c8 * 8) = zz;
}

// ---------------------------------------------------------------------------
// Pack ALL layers' weights in one launch:
// Wr[l] at offs[l], layout [dir][tap][80][ci_total(l)] bf16 (co >= 65 zeroed)
// ---------------------------------------------------------------------------
struct WP { const float* p[8]; };   // wf0,wb0,wf1,wb1,wf2,wb2,wf3,wb3

__global__ __launch_bounds__(256) void prep_w_all(WP wp, u16* __restrict__ Wr)
{
    int idx = blockIdx.x * 256 + threadIdx.x;
    if (idx >= 783360) return;
    const int offs[5] = {0, 92160, 230400, 460800, 783360};
    const int cit[4]  = {64, 96, 160, 224};
    int lay = 0;
    while (idx >= offs[lay + 1]) ++lay;
    int li = idx - offs[lay];
    int ci_total = cit[lay];
    int ci = li % ci_total;
    int rest = li / ci_total;
    int co = rest % 80; rest /= 80;
    int tap = rest % 9;
    int dir = rest / 9;
    const float* w = wp.p[lay * 2 + dir];
    float v = (co < 65) ? w[((size_t)co * ci_total + ci) * 9 + tap] : 0.f;
    Wr[idx] = f2bf(v);
}

// ---------------------------------------------------------------------------
// MFMA x-conv: frozen geometry (4 rows x 2 dirs, 25KB LDS, XCD-pinned img),
// NEW: T14 reg-staged async prefetch — chunk ch+1's global loads issue
// during chunk ch's MFMA chain; only reg->LDS writes sit between barriers.
// ---------------------------------------------------------------------------
__global__ __launch_bounds__(512, 2) void convx_mfma(
    const u16* __restrict__ XT, const u16* __restrict__ Wr,
    const float* __restrict__ b_f, const float* __restrict__ b_b,
    u16* __restrict__ convx, int cin, int ci_total)
{
    __shared__ u16 xs[6 * 66 * 32];       // 25,344 B
    const int tid = threadIdx.x;
    const int l = tid & 63, wv = tid >> 6;   // 8 waves
    const int g = l >> 4, ln16 = l & 15;
    const int img = blockIdx.x;              // t*4 + b  (fast dim -> XCD-pinned)
    const int dir = wv & 1;
    const int wrow = wv >> 1;                // 0..3
    const int r0  = blockIdx.z * 4;
    const int orow = r0 + wrow;

    const float* bias = dir ? b_b : b_f;
    f32x4 acc[5][4];
    #pragma unroll
    for (int mt = 0; mt < 5; ++mt)
        #pragma unroll
        for (int r = 0; r < 4; ++r) {
            int co = mt * 16 + g * 4 + r;
            float bv = (co < 65) ? bias[co] : 0.f;
            #pragma unroll
            for (int nt = 0; nt < 4; ++nt) acc[mt][nt][r] = bv;
        }

    const u16* wdir = Wr + (size_t)dir * 9 * 80 * ci_total + g * 8;
    const u16* xim  = XT + (size_t)img * 4356 * XSTR;

    // per-thread staging slots: idx = k*512 + tid, valid if idx < 1584
    short8 stg[4];
    int sidx[4];
    #pragma unroll
    for (int k = 0; k < 4; ++k) sidx[k] = k * 512 + tid;

#define ISSUE_LOADS(chv)                                                        \
    {                                                                           \
        _Pragma("unroll")                                                       \
        for (int k = 0; k < 4; ++k)                                             \
            if (sidx[k] < 1584)                                                 \
                stg[k] = *(const short8*)(xim + (size_t)(r0 * 66 +              \
                         (sidx[k] >> 2)) * XSTR + (chv) + (sidx[k] & 3) * 8);   \
    }

    ISSUE_LOADS(0)
    for (int ch = 0; ch < cin; ch += 32) {
        __syncthreads();                      // prev chunk's ds_reads done
        #pragma unroll
        for (int k = 0; k < 4; ++k)
            if (sidx[k] < 1584)
                *(short8*)(xs + (size_t)sidx[k] * 8) = stg[k];
        __syncthreads();                      // LDS ready
        if (ch + 32 < cin) ISSUE_LOADS(ch + 32)   // overlaps the MFMA chain

        #pragma unroll
        for (int ky = 0; ky < 3; ++ky) {
            #pragma unroll
            for (int kx = 0; kx < 3; ++kx) {
                const int tap = ky * 3 + kx;
                const u16* xb = xs + ((size_t)((wrow + ky) * 66 + ln16 + kx)) * 32 + g * 8;
                short8 bv0 = *(const short8*)(xb);
                short8 bv1 = *(const short8*)(xb + 16 * 32);
                short8 bv2 = *(const short8*)(xb + 32 * 32);
                short8 bv3 = *(const short8*)(xb + 48 * 32);
                const u16* wb_ = wdir + ((size_t)tap * 80 + ln16) * ci_total + ch;
                #pragma unroll
                for (int mt = 0; mt < 5; ++mt) {
                    short8 af = *(const short8*)(wb_ + (size_t)mt * 16 * ci_total);
                    acc[mt][0] = __builtin_amdgcn_mfma_f32_16x16x32_bf16(af, bv0, acc[mt][0], 0, 0, 0);
                    acc[mt][1] = __builtin_amdgcn_mfma_f32_16x16x32_bf16(af, bv1, acc[mt][1], 0, 0, 0);
                    acc[mt][2] = __builtin_amdgcn_mfma_f32_16x16x32_bf16(af, bv2, acc[mt][2], 0, 0, 0);
                    acc[mt][3] = __builtin_amdgcn_mfma_f32_16x16x32_bf16(af, bv3, acc[mt][3], 0, 0, 0);
                }
            }
        }
    }
#undef ISSUE_LOADS

    const int zimg = dir * 32 + img;
    u16* cb = convx + ((size_t)zimg * 64 + orow) * FR_ROW;
    #pragma unroll
    for (int mt = 0; mt < 4; ++mt)
        #pragma unroll
        for (int nt = 0; nt < 4; ++nt) {
            short4v pk;
            #pragma unroll
            for (int r = 0; r < 4; ++r) pk[r] = (short)f2bf(acc[mt][nt][r]);
            *(short4v*)(cb + (size_t)(nt * 4 + mt) * 256 + l * 4) = pk;
        }
    if (g == 0) {
        #pragma unroll
        for (int nt = 0; nt < 4; ++nt) {
            short4v pk;
            #pragma unroll
            for (int r = 0; r < 4; ++r) pk[r] = (short)f2bf(acc[4][nt][r]);
            *(short4v*)(cb + 4096 + nt * 64 + ln16 * 4) = pk;
        }
    }
}

// ---------------------------------------------------------------------------
// Recurrent step (r12/r15 version): role-split, deferred convx-add,
// XCD-pinned z. 8 waves = (2 rows x 2 col-halves) x 2 roles.
// ---------------------------------------------------------------------------
__global__ __launch_bounds__(512) void rec_mfma(
    const u16* __restrict__ cT_in, u16* __restrict__ cT_out,
    const u16* __restrict__ Wr, const u16* __restrict__ convx,
    float* __restrict__ out_t,
    float* __restrict__ lrh, float* __restrict__ lrc, float* __restrict__ lrg,
    u16* __restrict__ XT,
    int cin, int ci_total, int layer, int step)
{
    const int tid = threadIdx.x;
    const int l = tid & 63, w = tid >> 6;
    const int g = l >> 4, ln16 = l & 15;
    const int role = w & 1, ws = w >> 1;
    const int z = blockIdx.x;                  // dir*4 + b (fast dim -> XCD-pinned)
    const int dir = z >> 2, b = z & 3;
    const int t = dir ? (7 - step) : step;
    const int row  = blockIdx.z * 2 + (ws >> 1);
    const int nb   = (ws & 1) * 2;
    const int col0 = nb * 16;
    const int zimg = dir * 32 + t * 4 + b;
    const int m0 = role * 2;                   // this role's first mt

    // issue convx fragment loads early (consumed only in the epilogue)
    const u16* cxb = convx + ((size_t)zimg * 64 + row) * FR_ROW;
    short4v cx[3][2];
    #pragma unroll
    for (int j = 0; j < 2; ++j)
        #pragma unroll
        for (int nt = 0; nt < 2; ++nt)
            cx[j][nt] = *(const short4v*)(cxb + (size_t)((nb + nt) * 4 + (m0 + j)) * 256 + l * 4);
    #pragma unroll
    for (int nt = 0; nt < 2; ++nt)
        cx[2][nt] = (g == 0)
            ? *(const short4v*)(cxb + 4096 + (nb + nt) * 64 + ln16 * 4)
            : (short4v){0, 0, 0, 0};

    f32x4 acc[3][2] = {};
    if (step > 0) {
        const u16* wdir = Wr + (size_t)dir * 9 * 80 * ci_total + cin + g * 8;
        const u16* cim  = cT_in + (size_t)z * 4356 * 32 + g * 8;
        __builtin_amdgcn_s_setprio(1);
        #pragma unroll
        for (int ky = 0; ky < 3; ++ky) {
            #pragma unroll
            for (int kx = 0; kx < 3; ++kx) {
                const int tap = ky * 3 + kx;
                const u16* xb_ = cim + (size_t)((row + ky) * 66 + col0 + ln16 + kx) * 32;
                short8 bv0 = *(const short8*)(xb_);
                short8 bv1 = *(const short8*)(xb_ + 16 * 32);
                const u16* wb_ = wdir + ((size_t)tap * 80 + ln16) * ci_total;
                short8 af0 = *(const short8*)(wb_ + (size_t)(m0    ) * 16 * ci_total);
                short8 af1 = *(const short8*)(wb_ + (size_t)(m0 + 1) * 16 * ci_total);
                short8 af4 = *(const short8*)(wb_ + (size_t)4 * 16 * ci_total);
                acc[0][0] = __builtin_amdgcn_mfma_f32_16x16x32_bf16(af0, bv0, acc[0][0], 0, 0, 0);
                acc[0][1] = __builtin_amdgcn_mfma_f32_16x16x32_bf16(af0, bv1, acc[0][1], 0, 0, 0);
                acc[1][0] = __builtin_amdgcn_mfma_f32_16x16x32_bf16(af1, bv0, acc[1][0], 0, 0, 0);
                acc[1][1] = __builtin_amdgcn_mfma_f32_16x16x32_bf16(af1, bv1, acc[1][1], 0, 0, 0);
                acc[2][0] = __builtin_amdgcn_mfma_f32_16x16x32_bf16(af4, bv0, acc[2][0], 0, 0, 0);
                acc[2][1] = __builtin_amdgcn_mfma_f32_16x16x32_bf16(af4, bv1, acc[2][1], 0, 0, 0);
            }
        }
        __builtin_amdgcn_s_setprio(0);
    }

    const bool last_f = (dir == 0) && (step == 7);
    float val[2], gv[2];
    #pragma unroll
    for (int nt = 0; nt < 2; ++nt) {
        val[nt] = fsigm(ftanh(acc[2][nt][0] + bf2f((u16)cx[2][nt][0])));
        gv[nt]  = __shfl(val[nt], ln16);       // broadcast from g==0 lanes
    }

    if (role == 0) {
        // h epilogue: acc[j] is mt j -> co = j*16 + g*4 + r
        const size_t obase = (size_t)(t * 4 + b) * 256 + 64 * layer + dir * 32;
        const int chb = 64 * layer + dir * 32;
        #pragma unroll
        for (int j = 0; j < 2; ++j)
            #pragma unroll
            for (int nt = 0; nt < 2; ++nt) {
                int px = row * 64 + col0 + nt * 16 + ln16;
                short4v pkh;
                #pragma unroll
                for (int r = 0; r < 4; ++r) {
                    int co = j * 16 + g * 4 + r;
                    float v = ftanh(acc[j][nt][r] + bf2f((u16)cx[j][nt][r]));
                    out_t[(obase + co) * HW + px] = v;
                    pkh[r] = (short)f2bf(v);
                    if (last_f) lrh[((size_t)(layer * 4 + b) * 32 + co) * HW + px] = v;
                }
                if (layer < 3)
                    *(short4v*)(XT + ((size_t)(t * 4 + b) * 4356 + (row + 1) * 66 +
                                      (col0 + nt * 16 + ln16 + 1)) * XSTR + chb + j * 16 + g * 4) = pkh;
            }
        if (last_f && g == 0) {
            #pragma unroll
            for (int nt = 0; nt < 2; ++nt)
                lrg[(size_t)(layer * 4 + b) * HW + row * 64 + col0 + nt * 16 + ln16] = val[nt];
        }
    } else {
        // c epilogue: acc[j] is mt 2+j -> k = j*16 + g*4 + r
        #pragma unroll
        for (int j = 0; j < 2; ++j)
            #pragma unroll
            for (int nt = 0; nt < 2; ++nt) {
                short4v pk;
                #pragma unroll
                for (int r = 0; r < 4; ++r) {
                    int k = j * 16 + g * 4 + r;
                    float c = gv[nt] * ftanh(acc[j][nt][r] + bf2f((u16)cx[j][nt][r]));
                    pk[r] = (short)f2bf(c);
                    if (last_f)
                        lrc[((size_t)(layer * 4 + b) * 32 + k) * HW + row * 64 + col0 + nt * 16 + ln16] = c;
                }
                if (step < 7) {
                    int colh = col0 + nt * 16 + ln16 + 1;
                    *(short4v*)(cT_out + ((size_t)z * 4356 + (row + 1) * 66 + colh) * 32 + j * 16 + g * 4) = pk;
                }
            }
    }
}

extern "C" void kernel_launch(void* const* d_in, const int* in_sizes, int n_in,
                              void* d_out, int out_size, void* d_ws, size_t ws_size,
                              hipStream_t stream)
{
    const float* x = (const float*)d_in[0];
    float* out = (float*)d_out;                       // (8,4,256,64,64)
    float* lrh = out + (size_t)33554432;
    float* lrc = lrh + (size_t)2097152;
    float* lrg = lrc + (size_t)2097152;

    char* ws = (char*)d_ws;
    u16* convx = (u16*)ws;                            // 35,651,584 B
    size_t off = 35651584 + 4096;
    u16* cT_a = (u16*)(ws + off); off += 2230272;
    u16* cT_b = (u16*)(ws + off); off += 2230272;
    u16* XT = (u16*)(ws + off); off += 53526528;      // 32*4356*192*2
    u16* Wr = (u16*)(ws + off);                       // 1,566,720 B

    static const int offs[4] = {0, 92160, 230400, 460800};

    zero_border<<<dim3(780), 256, 0, stream>>>(XT);
    hipMemsetAsync(cT_a, 0, 2230272, stream);         // halos must stay 0
    hipMemsetAsync(cT_b, 0, 2230272, stream);
    transpose_halo<<<dim3(16, 1, 32), 256, 0, stream>>>(x, XT, 32);

    WP wp;
    for (int l = 0; l < 4; ++l) {
        wp.p[l * 2]     = (const float*)d_in[1 + 4 * l];
        wp.p[l * 2 + 1] = (const float*)d_in[3 + 4 * l];
    }
    prep_w_all<<<dim3((783360 + 255) / 256), 256, 0, stream>>>(wp, Wr);

    for (int l = 0; l < 4; ++l) {
        const float* bf = (const float*)d_in[2 + 4 * l];
        const float* bb = (const float*)d_in[4 + 4 * l];
        int cin = (l == 0) ? 32 : 64 * l;
        int ci_total = cin + 32;
        const u16* Wrl = Wr + offs[l];

        convx_mfma<<<dim3(32, 1, 16), 512, 0, stream>>>(XT, Wrl, bf, bb, convx, cin, ci_total);

        for (int s = 0; s < 8; ++s) {
            const u16* cin_p = (s & 1) ? cT_b : cT_a;
            u16* cout_p      = (s & 1) ? cT_a : cT_b;
            rec_mfma<<<dim3(8, 1, 32), 512, 0, stream>>>(
                cin_p, cout_p, Wrl, convx, out, lrh, lrc, lrg, XT,
                cin, ci_total, l, s);
        }
    }
}

// Round 17
// 705.177 us; speedup vs baseline: 1.0197x; 1.0197x over previous
//
#include <hip/hip_runtime.h>
#include <math.h>

#define T_STEPS 8
#define HW 4096
#define XSTR 192                    // XT channel stride (fixed, max cin)
#define FR_ROW 4352                 // convx u16 per (img,row)

typedef unsigned short u16;
typedef __attribute__((ext_vector_type(8))) short short8;
typedef __attribute__((ext_vector_type(4))) short short4v;
typedef __attribute__((ext_vector_type(4))) float f32x4;

__device__ __forceinline__ u16 f2bf(float f) {
    unsigned u = __builtin_bit_cast(unsigned, f);
    u += 0x7fffu + ((u >> 16) & 1u);
    return (u16)(u >> 16);
}
__device__ __forceinline__ float bf2f(u16 h) {
    unsigned u = ((unsigned)h) << 16;
    return __builtin_bit_cast(float, u);
}
__device__ __forceinline__ float ftanh(float x) {
    float e = __expf(2.f * x);
    return 1.f - 2.f * __builtin_amdgcn_rcpf(e + 1.f);
}
__device__ __forceinline__ float fsigm(float x) {
    return __builtin_amdgcn_rcpf(1.f + __expf(-x));
}

// ---------------------------------------------------------------------------
// l0 only: fp32 x [img][32][64][64] -> bf16 XT[img][66][66][192] ch 0..31
// ---------------------------------------------------------------------------
__global__ __launch_bounds__(256) void transpose_halo(
    const float* __restrict__ src, u16* __restrict__ XT, int src_ctot)
{
    __shared__ float tile[32][257];
    const int img = blockIdx.z;
    const int px0 = blockIdx.x * 256;
    const float* s = src + (size_t)img * src_ctot * HW + px0;
    #pragma unroll
    for (int c = 0; c < 32; ++c)
        tile[c][threadIdx.x] = s[(size_t)c * HW + threadIdx.x];
    __syncthreads();
    const int c = threadIdx.x & 31, pb = threadIdx.x >> 5;
    const int r0 = px0 >> 6;
    for (int p = pb; p < 256; p += 8) {
        int row = r0 + (p >> 6), col = p & 63;
        XT[((size_t)img * 4356 + (row + 1) * 66 + col + 1) * XSTR + c] = f2bf(tile[c][p]);
    }
}

// ---------------------------------------------------------------------------
// Zero only XT's halo border cells (260 px/img, all 192 ch)
// ---------------------------------------------------------------------------
__global__ __launch_bounds__(256) void zero_border(u16* __restrict__ XT)
{
    int idx = blockIdx.x * 256 + threadIdx.x;      // 32*260*24 = 199,680
    if (idx >= 199680) return;
    int c8 = idx % 24;
    int rest = idx / 24;
    int bp = rest % 260;
    int img = rest / 260;
    int row, col;
    if (bp < 66)       { row = 0;  col = bp; }
    else if (bp < 132) { row = 65; col = bp - 66; }
    else if (bp < 196) { col = 0;  row = 1 + bp - 132; }
    else               { col = 65; row = 1 + bp - 196; }
    short8 zz = {0, 0, 0, 0, 0, 0, 0, 0};
    *(short8*)(XT + ((size_t)img * 4356 + row * 66 + col) * XSTR + c8 * 8) = zz;
}

// ---------------------------------------------------------------------------
// Pack ALL layers' weights in one launch:
// Wr[l] at offs[l], layout [dir][tap][80][ci_total(l)] bf16 (co >= 65 zeroed)
// ---------------------------------------------------------------------------
struct WP { const float* p[8]; };   // wf0,wb0,wf1,wb1,wf2,wb2,wf3,wb3

__global__ __launch_bounds__(256) void prep_w_all(WP wp, u16* __restrict__ Wr)
{
    int idx = blockIdx.x * 256 + threadIdx.x;
    if (idx >= 783360) return;
    const int offs[5] = {0, 92160, 230400, 460800, 783360};
    const int cit[4]  = {64, 96, 160, 224};
    int lay = 0;
    while (idx >= offs[lay + 1]) ++lay;
    int li = idx - offs[lay];
    int ci_total = cit[lay];
    int ci = li % ci_total;
    int rest = li / ci_total;
    int co = rest % 80; rest /= 80;
    int tap = rest % 9;
    int dir = rest / 9;
    const float* w = wp.p[lay * 2 + dir];
    float v = (co < 65) ? w[((size_t)co * ci_total + ci) * 9 + tap] : 0.f;
    Wr[idx] = f2bf(v);
}

// ---------------------------------------------------------------------------
// MFMA x-conv: frozen per-wave body (1 row x 80 co x 64 px, 64 VGPR,
// 25KB LDS stage). NEW grid: (img, dir, rb) — dir split across blocks ->
// 1024 blocks = 4/CU (vs 2), more independent barrier-domains interleave;
// img on the fast dim keeps both dir-blocks of an image on one XCD so the
// second dir's stage fetch hits that XCD's L2.
// ---------------------------------------------------------------------------
__global__ __launch_bounds__(256, 4) void convx_mfma(
    const u16* __restrict__ XT, const u16* __restrict__ Wr,
    const float* __restrict__ b_f, const float* __restrict__ b_b,
    u16* __restrict__ convx, int cin, int ci_total)
{
    __shared__ u16 xs[6 * 66 * 32];       // 25,344 B
    const int tid = threadIdx.x;
    const int l = tid & 63, wrow = tid >> 6;   // 4 waves = 4 rows
    const int g = l >> 4, ln16 = l & 15;
    const int img = blockIdx.x;              // t*4 + b  (fast dim -> XCD-pinned)
    const int dir = blockIdx.y;
    const int r0  = blockIdx.z * 4;
    const int orow = r0 + wrow;

    const float* bias = dir ? b_b : b_f;
    f32x4 acc[5][4];
    #pragma unroll
    for (int mt = 0; mt < 5; ++mt)
        #pragma unroll
        for (int r = 0; r < 4; ++r) {
            int co = mt * 16 + g * 4 + r;
            float bv = (co < 65) ? bias[co] : 0.f;
            #pragma unroll
            for (int nt = 0; nt < 4; ++nt) acc[mt][nt][r] = bv;
        }

    const u16* wdir = Wr + (size_t)dir * 9 * 80 * ci_total + g * 8;
    const u16* xim  = XT + (size_t)img * 4356 * XSTR;

    for (int ch = 0; ch < cin; ch += 32) {
        __syncthreads();
        // stage rows r0..r0+5, 66 px, 32 ch -> 1584 x 16B across 256 threads
        #pragma unroll
        for (int k = 0; k < 7; ++k) {
            int idx = k * 256 + tid;
            if (idx < 1584) {
                int seg = idx & 3;
                int pr  = idx >> 2;
                short8 v = *(const short8*)(xim + (size_t)(r0 * 66 + pr) * XSTR + ch + seg * 8);
                *(short8*)(xs + (size_t)idx * 8) = v;
            }
        }
        __syncthreads();

        #pragma unroll
        for (int ky = 0; ky < 3; ++ky) {
            #pragma unroll
            for (int kx = 0; kx < 3; ++kx) {
                const int tap = ky * 3 + kx;
                const u16* xb = xs + ((size_t)((wrow + ky) * 66 + ln16 + kx)) * 32 + g * 8;
                short8 bv0 = *(const short8*)(xb);
                short8 bv1 = *(const short8*)(xb + 16 * 32);
                short8 bv2 = *(const short8*)(xb + 32 * 32);
                short8 bv3 = *(const short8*)(xb + 48 * 32);
                const u16* wb_ = wdir + ((size_t)tap * 80 + ln16) * ci_total + ch;
                #pragma unroll
                for (int mt = 0; mt < 5; ++mt) {
                    short8 af = *(const short8*)(wb_ + (size_t)mt * 16 * ci_total);
                    acc[mt][0] = __builtin_amdgcn_mfma_f32_16x16x32_bf16(af, bv0, acc[mt][0], 0, 0, 0);
                    acc[mt][1] = __builtin_amdgcn_mfma_f32_16x16x32_bf16(af, bv1, acc[mt][1], 0, 0, 0);
                    acc[mt][2] = __builtin_amdgcn_mfma_f32_16x16x32_bf16(af, bv2, acc[mt][2], 0, 0, 0);
                    acc[mt][3] = __builtin_amdgcn_mfma_f32_16x16x32_bf16(af, bv3, acc[mt][3], 0, 0, 0);
                }
            }
        }
    }

    const int zimg = dir * 32 + img;
    u16* cb = convx + ((size_t)zimg * 64 + orow) * FR_ROW;
    #pragma unroll
    for (int mt = 0; mt < 4; ++mt)
        #pragma unroll
        for (int nt = 0; nt < 4; ++nt) {
            short4v pk;
            #pragma unroll
            for (int r = 0; r < 4; ++r) pk[r] = (short)f2bf(acc[mt][nt][r]);
            *(short4v*)(cb + (size_t)(nt * 4 + mt) * 256 + l * 4) = pk;
        }
    if (g == 0) {
        #pragma unroll
        for (int nt = 0; nt < 4; ++nt) {
            short4v pk;
            #pragma unroll
            for (int r = 0; r < 4; ++r) pk[r] = (short)f2bf(acc[4][nt][r]);
            *(short4v*)(cb + 4096 + nt * 64 + ln16 * 4) = pk;
        }
    }
}

// ---------------------------------------------------------------------------
// Recurrent step (r12/r15 version — unchanged): role-split, deferred
// convx-add, XCD-pinned z. 8 waves = (2 rows x 2 col-halves) x 2 roles.
// ---------------------------------------------------------------------------
__global__ __launch_bounds__(512) void rec_mfma(
    const u16* __restrict__ cT_in, u16* __restrict__ cT_out,
    const u16* __restrict__ Wr, const u16* __restrict__ convx,
    float* __restrict__ out_t,
    float* __restrict__ lrh, float* __restrict__ lrc, float* __restrict__ lrg,
    u16* __restrict__ XT,
    int cin, int ci_total, int layer, int step)
{
    const int tid = threadIdx.x;
    const int l = tid & 63, w = tid >> 6;
    const int g = l >> 4, ln16 = l & 15;
    const int role = w & 1, ws = w >> 1;
    const int z = blockIdx.x;                  // dir*4 + b (fast dim -> XCD-pinned)
    const int dir = z >> 2, b = z & 3;
    const int t = dir ? (7 - step) : step;
    const int row  = blockIdx.z * 2 + (ws >> 1);
    const int nb   = (ws & 1) * 2;
    const int col0 = nb * 16;
    const int zimg = dir * 32 + t * 4 + b;
    const int m0 = role * 2;                   // this role's first mt

    // issue convx fragment loads early (consumed only in the epilogue)
    const u16* cxb = convx + ((size_t)zimg * 64 + row) * FR_ROW;
    short4v cx[3][2];
    #pragma unroll
    for (int j = 0; j < 2; ++j)
        #pragma unroll
        for (int nt = 0; nt < 2; ++nt)
            cx[j][nt] = *(const short4v*)(cxb + (size_t)((nb + nt) * 4 + (m0 + j)) * 256 + l * 4);
    #pragma unroll
    for (int nt = 0; nt < 2; ++nt)
        cx[2][nt] = (g == 0)
            ? *(const short4v*)(cxb + 4096 + (nb + nt) * 64 + ln16 * 4)
            : (short4v){0, 0, 0, 0};

    f32x4 acc[3][2] = {};
    if (step > 0) {
        const u16* wdir = Wr + (size_t)dir * 9 * 80 * ci_total + cin + g * 8;
        const u16* cim  = cT_in + (size_t)z * 4356 * 32 + g * 8;
        __builtin_amdgcn_s_setprio(1);
        #pragma unroll
        for (int ky = 0; ky < 3; ++ky) {
            #pragma unroll
            for (int kx = 0; kx < 3; ++kx) {
                const int tap = ky * 3 + kx;
                const u16* xb_ = cim + (size_t)((row + ky) * 66 + col0 + ln16 + kx) * 32;
                short8 bv0 = *(const short8*)(xb_);
                short8 bv1 = *(const short8*)(xb_ + 16 * 32);
                const u16* wb_ = wdir + ((size_t)tap * 80 + ln16) * ci_total;
                short8 af0 = *(const short8*)(wb_ + (size_t)(m0    ) * 16 * ci_total);
                short8 af1 = *(const short8*)(wb_ + (size_t)(m0 + 1) * 16 * ci_total);
                short8 af4 = *(const short8*)(wb_ + (size_t)4 * 16 * ci_total);
                acc[0][0] = __builtin_amdgcn_mfma_f32_16x16x32_bf16(af0, bv0, acc[0][0], 0, 0, 0);
                acc[0][1] = __builtin_amdgcn_mfma_f32_16x16x32_bf16(af0, bv1, acc[0][1], 0, 0, 0);
                acc[1][0] = __builtin_amdgcn_mfma_f32_16x16x32_bf16(af1, bv0, acc[1][0], 0, 0, 0);
                acc[1][1] = __builtin_amdgcn_mfma_f32_16x16x32_bf16(af1, bv1, acc[1][1], 0, 0, 0);
                acc[2][0] = __builtin_amdgcn_mfma_f32_16x16x32_bf16(af4, bv0, acc[2][0], 0, 0, 0);
                acc[2][1] = __builtin_amdgcn_mfma_f32_16x16x32_bf16(af4, bv1, acc[2][1], 0, 0, 0);
            }
        }
        __builtin_amdgcn_s_setprio(0);
    }

    const bool last_f = (dir == 0) && (step == 7);
    float val[2], gv[2];
    #pragma unroll
    for (int nt = 0; nt < 2; ++nt) {
        val[nt] = fsigm(ftanh(acc[2][nt][0] + bf2f((u16)cx[2][nt][0])));
        gv[nt]  = __shfl(val[nt], ln16);       // broadcast from g==0 lanes
    }

    if (role == 0) {
        // h epilogue: acc[j] is mt j -> co = j*16 + g*4 + r
        const size_t obase = (size_t)(t * 4 + b) * 256 + 64 * layer + dir * 32;
        const int chb = 64 * layer + dir * 32;
        #pragma unroll
        for (int j = 0; j < 2; ++j)
            #pragma unroll
            for (int nt = 0; nt < 2; ++nt) {
                int px = row * 64 + col0 + nt * 16 + ln16;
                short4v pkh;
                #pragma unroll
                for (int r = 0; r < 4; ++r) {
                    int co = j * 16 + g * 4 + r;
                    float v = ftanh(acc[j][nt][r] + bf2f((u16)cx[j][nt][r]));
                    out_t[(obase + co) * HW + px] = v;
                    pkh[r] = (short)f2bf(v);
                    if (last_f) lrh[((size_t)(layer * 4 + b) * 32 + co) * HW + px] = v;
                }
                if (layer < 3)
                    *(short4v*)(XT + ((size_t)(t * 4 + b) * 4356 + (row + 1) * 66 +
                                      (col0 + nt * 16 + ln16 + 1)) * XSTR + chb + j * 16 + g * 4) = pkh;
            }
        if (last_f && g == 0) {
            #pragma unroll
            for (int nt = 0; nt < 2; ++nt)
                lrg[(size_t)(layer * 4 + b) * HW + row * 64 + col0 + nt * 16 + ln16] = val[nt];
        }
    } else {
        // c epilogue: acc[j] is mt 2+j -> k = j*16 + g*4 + r
        #pragma unroll
        for (int j = 0; j < 2; ++j)
            #pragma unroll
            for (int nt = 0; nt < 2; ++nt) {
                short4v pk;
                #pragma unroll
                for (int r = 0; r < 4; ++r) {
                    int k = j * 16 + g * 4 + r;
                    float c = gv[nt] * ftanh(acc[j][nt][r] + bf2f((u16)cx[j][nt][r]));
                    pk[r] = (short)f2bf(c);
                    if (last_f)
                        lrc[((size_t)(layer * 4 + b) * 32 + k) * HW + row * 64 + col0 + nt * 16 + ln16] = c;
                }
                if (step < 7) {
                    int colh = col0 + nt * 16 + ln16 + 1;
                    *(short4v*)(cT_out + ((size_t)z * 4356 + (row + 1) * 66 + colh) * 32 + j * 16 + g * 4) = pk;
                }
            }
    }
}

extern "C" void kernel_launch(void* const* d_in, const int* in_sizes, int n_in,
                              void* d_out, int out_size, void* d_ws, size_t ws_size,
                              hipStream_t stream)
{
    const float* x = (const float*)d_in[0];
    float* out = (float*)d_out;                       // (8,4,256,64,64)
    float* lrh = out + (size_t)33554432;
    float* lrc = lrh + (size_t)2097152;
    float* lrg = lrc + (size_t)2097152;

    char* ws = (char*)d_ws;
    u16* convx = (u16*)ws;                            // 35,651,584 B
    size_t off = 35651584 + 4096;
    u16* cT_a = (u16*)(ws + off); off += 2230272;
    u16* cT_b = (u16*)(ws + off); off += 2230272;
    u16* XT = (u16*)(ws + off); off += 53526528;      // 32*4356*192*2
    u16* Wr = (u16*)(ws + off);                       // 1,566,720 B

    static const int offs[4] = {0, 92160, 230400, 460800};

    zero_border<<<dim3(780), 256, 0, stream>>>(XT);
    hipMemsetAsync(cT_a, 0, 2230272, stream);         // halos must stay 0
    hipMemsetAsync(cT_b, 0, 2230272, stream);
    transpose_halo<<<dim3(16, 1, 32), 256, 0, stream>>>(x, XT, 32);

    WP wp;
    for (int l = 0; l < 4; ++l) {
        wp.p[l * 2]     = (const float*)d_in[1 + 4 * l];
        wp.p[l * 2 + 1] = (const float*)d_in[3 + 4 * l];
    }
    prep_w_all<<<dim3((783360 + 255) / 256), 256, 0, stream>>>(wp, Wr);

    for (int l = 0; l < 4; ++l) {
        const float* bf = (const float*)d_in[2 + 4 * l];
        const float* bb = (const float*)d_in[4 + 4 * l];
        int cin = (l == 0) ? 32 : 64 * l;
        int ci_total = cin + 32;
        const u16* Wrl = Wr + offs[l];

        convx_mfma<<<dim3(32, 2, 16), 256, 0, stream>>>(XT, Wrl, bf, bb, convx, cin, ci_total);

        for (int s = 0; s < 8; ++s) {
            const u16* cin_p = (s & 1) ? cT_b : cT_a;
            u16* cout_p      = (s & 1) ? cT_a : cT_b;
            rec_mfma<<<dim3(8, 1, 32), 512, 0, stream>>>(
                cin_p, cout_p, Wrl, convx, out, lrh, lrc, lrg, XT,
                cin, ci_total, l, s);
        }
    }
}

// Round 18
// 560.866 us; speedup vs baseline: 1.2821x; 1.2573x over previous
//
#include <hip/hip_runtime.h>
#include <math.h>

#define T_STEPS 8
#define HW 4096
#define XSTR 192                    // XT channel stride (fixed, max cin)
#define FR_ROW 4352                 // convx u16 per (img,row)

typedef unsigned short u16;
typedef __attribute__((ext_vector_type(8))) short short8;
typedef __attribute__((ext_vector_type(4))) short short4v;
typedef __attribute__((ext_vector_type(4))) float f32x4;

__device__ __forceinline__ u16 f2bf(float f) {
    unsigned u = __builtin_bit_cast(unsigned, f);
    u += 0x7fffu + ((u >> 16) & 1u);
    return (u16)(u >> 16);
}
__device__ __forceinline__ float bf2f(u16 h) {
    unsigned u = ((unsigned)h) << 16;
    return __builtin_bit_cast(float, u);
}
__device__ __forceinline__ float ftanh(float x) {
    float e = __expf(2.f * x);
    return 1.f - 2.f * __builtin_amdgcn_rcpf(e + 1.f);
}
__device__ __forceinline__ float fsigm(float x) {
    return __builtin_amdgcn_rcpf(1.f + __expf(-x));
}

// ---------------------------------------------------------------------------
// l0 only: fp32 x [img][32][64][64] -> bf16 XT[img][66][66][192] ch 0..31
// ---------------------------------------------------------------------------
__global__ __launch_bounds__(256) void transpose_halo(
    const float* __restrict__ src, u16* __restrict__ XT, int src_ctot)
{
    __shared__ float tile[32][257];
    const int img = blockIdx.z;
    const int px0 = blockIdx.x * 256;
    const float* s = src + (size_t)img * src_ctot * HW + px0;
    #pragma unroll
    for (int c = 0; c < 32; ++c)
        tile[c][threadIdx.x] = s[(size_t)c * HW + threadIdx.x];
    __syncthreads();
    const int c = threadIdx.x & 31, pb = threadIdx.x >> 5;
    const int r0 = px0 >> 6;
    for (int p = pb; p < 256; p += 8) {
        int row = r0 + (p >> 6), col = p & 63;
        XT[((size_t)img * 4356 + (row + 1) * 66 + col + 1) * XSTR + c] = f2bf(tile[c][p]);
    }
}

// ---------------------------------------------------------------------------
// Zero only XT's halo border cells (260 px/img, all 192 ch)
// ---------------------------------------------------------------------------
__global__ __launch_bounds__(256) void zero_border(u16* __restrict__ XT)
{
    int idx = blockIdx.x * 256 + threadIdx.x;      // 32*260*24 = 199,680
    if (idx >= 199680) return;
    int c8 = idx % 24;
    int rest = idx / 24;
    int bp = rest % 260;
    int img = rest / 260;
    int row, col;
    if (bp < 66)       { row = 0;  col = bp; }
    else if (bp < 132) { row = 65; col = bp - 66; }
    else if (bp < 196) { col = 0;  row = 1 + bp - 132; }
    else               { col = 65; row = 1 + bp - 196; }
    short8 zz = {0, 0, 0, 0, 0, 0, 0, 0};
    *(short8*)(XT + ((size_t)img * 4356 + row * 66 + col) * XSTR + c8 * 8) = zz;
}

// ---------------------------------------------------------------------------
// Pack ALL layers' weights in one launch:
// Wr[l] at offs[l], layout [dir][tap][80][ci_total(l)] bf16 (co >= 65 zeroed)
// ---------------------------------------------------------------------------
struct WP { const float* p[8]; };   // wf0,wb0,wf1,wb1,wf2,wb2,wf3,wb3

__global__ __launch_bounds__(256) void prep_w_all(WP wp, u16* __restrict__ Wr)
{
    int idx = blockIdx.x * 256 + threadIdx.x;
    if (idx >= 783360) return;
    const int offs[5] = {0, 92160, 230400, 460800, 783360};
    const int cit[4]  = {64, 96, 160, 224};
    int lay = 0;
    while (idx >= offs[lay + 1]) ++lay;
    int li = idx - offs[lay];
    int ci_total = cit[lay];
    int ci = li % ci_total;
    int rest = li / ci_total;
    int co = rest % 80; rest /= 80;
    int tap = rest % 9;
    int dir = rest / 9;
    const float* w = wp.p[lay * 2 + dir];
    float v = (co < 65) ? w[((size_t)co * ci_total + ci) * 9 + tap] : 0.f;
    Wr[idx] = f2bf(v);
}

// ---------------------------------------------------------------------------
// MFMA x-conv (FROZEN body): dir-fused, single 25KB LDS stage; 8 waves =
// 4 rows x 2 dirs. XCD-locality grid: img = blockIdx.x (fast dim) so all
// row-blocks of an image share one XCD's L2 (halo + weight reuse local).
// ---------------------------------------------------------------------------
__global__ __launch_bounds__(512, 2) void convx_mfma(
    const u16* __restrict__ XT, const u16* __restrict__ Wr,
    const float* __restrict__ b_f, const float* __restrict__ b_b,
    u16* __restrict__ convx, int cin, int ci_total)
{
    __shared__ u16 xs[6 * 66 * 32];       // 25,344 B
    const int tid = threadIdx.x;
    const int l = tid & 63, wv = tid >> 6;   // 8 waves
    const int g = l >> 4, ln16 = l & 15;
    const int img = blockIdx.x;              // t*4 + b  (fast dim -> XCD-pinned)
    const int dir = wv & 1;
    const int wrow = wv >> 1;                // 0..3
    const int r0  = blockIdx.z * 4;
    const int orow = r0 + wrow;

    const float* bias = dir ? b_b : b_f;
    f32x4 acc[5][4];
    #pragma unroll
    for (int mt = 0; mt < 5; ++mt)
        #pragma unroll
        for (int r = 0; r < 4; ++r) {
            int co = mt * 16 + g * 4 + r;
            float bv = (co < 65) ? bias[co] : 0.f;
            #pragma unroll
            for (int nt = 0; nt < 4; ++nt) acc[mt][nt][r] = bv;
        }

    const u16* wdir = Wr + (size_t)dir * 9 * 80 * ci_total + g * 8;
    const u16* xim  = XT + (size_t)img * 4356 * XSTR;

    for (int ch = 0; ch < cin; ch += 32) {
        __syncthreads();
        // stage rows r0..r0+5, 66 px, 32 ch -> 1584 x 16B across 512 threads
        #pragma unroll
        for (int k = 0; k < 4; ++k) {
            int idx = k * 512 + tid;
            if (idx < 1584) {
                int seg = idx & 3;
                int pr  = idx >> 2;
                short8 v = *(const short8*)(xim + (size_t)(r0 * 66 + pr) * XSTR + ch + seg * 8);
                *(short8*)(xs + (size_t)idx * 8) = v;
            }
        }
        __syncthreads();

        #pragma unroll
        for (int ky = 0; ky < 3; ++ky) {
            #pragma unroll
            for (int kx = 0; kx < 3; ++kx) {
                const int tap = ky * 3 + kx;
                const u16* xb = xs + ((size_t)((wrow + ky) * 66 + ln16 + kx)) * 32 + g * 8;
                short8 bv0 = *(const short8*)(xb);
                short8 bv1 = *(const short8*)(xb + 16 * 32);
                short8 bv2 = *(const short8*)(xb + 32 * 32);
                short8 bv3 = *(const short8*)(xb + 48 * 32);
                const u16* wb_ = wdir + ((size_t)tap * 80 + ln16) * ci_total + ch;
                #pragma unroll
                for (int mt = 0; mt < 5; ++mt) {
                    short8 af = *(const short8*)(wb_ + (size_t)mt * 16 * ci_total);
                    acc[mt][0] = __builtin_amdgcn_mfma_f32_16x16x32_bf16(af, bv0, acc[mt][0], 0, 0, 0);
                    acc[mt][1] = __builtin_amdgcn_mfma_f32_16x16x32_bf16(af, bv1, acc[mt][1], 0, 0, 0);
                    acc[mt][2] = __builtin_amdgcn_mfma_f32_16x16x32_bf16(af, bv2, acc[mt][2], 0, 0, 0);
                    acc[mt][3] = __builtin_amdgcn_mfma_f32_16x16x32_bf16(af, bv3, acc[mt][3], 0, 0, 0);
                }
            }
        }
    }

    const int zimg = dir * 32 + img;
    u16* cb = convx + ((size_t)zimg * 64 + orow) * FR_ROW;
    #pragma unroll
    for (int mt = 0; mt < 4; ++mt)
        #pragma unroll
        for (int nt = 0; nt < 4; ++nt) {
            short4v pk;
            #pragma unroll
            for (int r = 0; r < 4; ++r) pk[r] = (short)f2bf(acc[mt][nt][r]);
            *(short4v*)(cb + (size_t)(nt * 4 + mt) * 256 + l * 4) = pk;
        }
    if (g == 0) {
        #pragma unroll
        for (int nt = 0; nt < 4; ++nt) {
            short4v pk;
            #pragma unroll
            for (int r = 0; r < 4; ++r) pk[r] = (short)f2bf(acc[4][nt][r]);
            *(short4v*)(cb + 4096 + nt * 64 + ln16 * 4) = pk;
        }
    }
}

// ---------------------------------------------------------------------------
// Recurrent step (r12 version): role-split, deferred convx-add. 8 waves =
// (2 rows x 2 col-halves) x 2 roles; step 0 skips conv; step 7 skips cT
// store. XCD-locality grid: z = blockIdx.x (fast dim) pins each z-chain's
// cT slab + halos to one XCD.
// ---------------------------------------------------------------------------
__global__ __launch_bounds__(512) void rec_mfma(
    const u16* __restrict__ cT_in, u16* __restrict__ cT_out,
    const u16* __restrict__ Wr, const u16* __restrict__ convx,
    float* __restrict__ out_t,
    float* __restrict__ lrh, float* __restrict__ lrc, float* __restrict__ lrg,
    u16* __restrict__ XT,
    int cin, int ci_total, int layer, int step)
{
    const int tid = threadIdx.x;
    const int l = tid & 63, w = tid >> 6;
    const int g = l >> 4, ln16 = l & 15;
    const int role = w & 1, ws = w >> 1;
    const int z = blockIdx.x;                  // dir*4 + b (fast dim -> XCD-pinned)
    const int dir = z >> 2, b = z & 3;
    const int t = dir ? (7 - step) : step;
    const int row  = blockIdx.z * 2 + (ws >> 1);
    const int nb   = (ws & 1) * 2;
    const int col0 = nb * 16;
    const int zimg = dir * 32 + t * 4 + b;
    const int m0 = role * 2;                   // this role's first mt

    // issue convx fragment loads early (consumed only in the epilogue)
    const u16* cxb = convx + ((size_t)zimg * 64 + row) * FR_ROW;
    short4v cx[3][2];
    #pragma unroll
    for (int j = 0; j < 2; ++j)
        #pragma unroll
        for (int nt = 0; nt < 2; ++nt)
            cx[j][nt] = *(const short4v*)(cxb + (size_t)((nb + nt) * 4 + (m0 + j)) * 256 + l * 4);
    #pragma unroll
    for (int nt = 0; nt < 2; ++nt)
        cx[2][nt] = (g == 0)
            ? *(const short4v*)(cxb + 4096 + (nb + nt) * 64 + ln16 * 4)
            : (short4v){0, 0, 0, 0};

    f32x4 acc[3][2] = {};
    if (step > 0) {
        const u16* wdir = Wr + (size_t)dir * 9 * 80 * ci_total + cin + g * 8;
        const u16* cim  = cT_in + (size_t)z * 4356 * 32 + g * 8;
        __builtin_amdgcn_s_setprio(1);
        #pragma unroll
        for (int ky = 0; ky < 3; ++ky) {
            #pragma unroll
            for (int kx = 0; kx < 3; ++kx) {
                const int tap = ky * 3 + kx;
                const u16* xb_ = cim + (size_t)((row + ky) * 66 + col0 + ln16 + kx) * 32;
                short8 bv0 = *(const short8*)(xb_);
                short8 bv1 = *(const short8*)(xb_ + 16 * 32);
                const u16* wb_ = wdir + ((size_t)tap * 80 + ln16) * ci_total;
                short8 af0 = *(const short8*)(wb_ + (size_t)(m0    ) * 16 * ci_total);
                short8 af1 = *(const short8*)(wb_ + (size_t)(m0 + 1) * 16 * ci_total);
                short8 af4 = *(const short8*)(wb_ + (size_t)4 * 16 * ci_total);
                acc[0][0] = __builtin_amdgcn_mfma_f32_16x16x32_bf16(af0, bv0, acc[0][0], 0, 0, 0);
                acc[0][1] = __builtin_amdgcn_mfma_f32_16x16x32_bf16(af0, bv1, acc[0][1], 0, 0, 0);
                acc[1][0] = __builtin_amdgcn_mfma_f32_16x16x32_bf16(af1, bv0, acc[1][0], 0, 0, 0);
                acc[1][1] = __builtin_amdgcn_mfma_f32_16x16x32_bf16(af1, bv1, acc[1][1], 0, 0, 0);
                acc[2][0] = __builtin_amdgcn_mfma_f32_16x16x32_bf16(af4, bv0, acc[2][0], 0, 0, 0);
                acc[2][1] = __builtin_amdgcn_mfma_f32_16x16x32_bf16(af4, bv1, acc[2][1], 0, 0, 0);
            }
        }
        __builtin_amdgcn_s_setprio(0);
    }

    const bool last_f = (dir == 0) && (step == 7);
    float val[2], gv[2];
    #pragma unroll
    for (int nt = 0; nt < 2; ++nt) {
        val[nt] = fsigm(ftanh(acc[2][nt][0] + bf2f((u16)cx[2][nt][0])));
        gv[nt]  = __shfl(val[nt], ln16);       // broadcast from g==0 lanes
    }

    if (role == 0) {
        // h epilogue: acc[j] is mt j -> co = j*16 + g*4 + r
        const size_t obase = (size_t)(t * 4 + b) * 256 + 64 * layer + dir * 32;
        const int chb = 64 * layer + dir * 32;
        #pragma unroll
        for (int j = 0; j < 2; ++j)
            #pragma unroll
            for (int nt = 0; nt < 2; ++nt) {
                int px = row * 64 + col0 + nt * 16 + ln16;
                short4v pkh;
                #pragma unroll
                for (int r = 0; r < 4; ++r) {
                    int co = j * 16 + g * 4 + r;
                    float v = ftanh(acc[j][nt][r] + bf2f((u16)cx[j][nt][r]));
                    out_t[(obase + co) * HW + px] = v;
                    pkh[r] = (short)f2bf(v);
                    if (last_f) lrh[((size_t)(layer * 4 + b) * 32 + co) * HW + px] = v;
                }
                if (layer < 3)
                    *(short4v*)(XT + ((size_t)(t * 4 + b) * 4356 + (row + 1) * 66 +
                                      (col0 + nt * 16 + ln16 + 1)) * XSTR + chb + j * 16 + g * 4) = pkh;
            }
        if (last_f && g == 0) {
            #pragma unroll
            for (int nt = 0; nt < 2; ++nt)
                lrg[(size_t)(layer * 4 + b) * HW + row * 64 + col0 + nt * 16 + ln16] = val[nt];
        }
    } else {
        // c epilogue: acc[j] is mt 2+j -> k = j*16 + g*4 + r
        #pragma unroll
        for (int j = 0; j < 2; ++j)
            #pragma unroll
            for (int nt = 0; nt < 2; ++nt) {
                short4v pk;
                #pragma unroll
                for (int r = 0; r < 4; ++r) {
                    int k = j * 16 + g * 4 + r;
                    float c = gv[nt] * ftanh(acc[j][nt][r] + bf2f((u16)cx[j][nt][r]));
                    pk[r] = (short)f2bf(c);
                    if (last_f)
                        lrc[((size_t)(layer * 4 + b) * 32 + k) * HW + row * 64 + col0 + nt * 16 + ln16] = c;
                }
                if (step < 7) {
                    int colh = col0 + nt * 16 + ln16 + 1;
                    *(short4v*)(cT_out + ((size_t)z * 4356 + (row + 1) * 66 + colh) * 32 + j * 16 + g * 4) = pk;
                }
            }
    }
}

extern "C" void kernel_launch(void* const* d_in, const int* in_sizes, int n_in,
                              void* d_out, int out_size, void* d_ws, size_t ws_size,
                              hipStream_t stream)
{
    const float* x = (const float*)d_in[0];
    float* out = (float*)d_out;                       // (8,4,256,64,64)
    float* lrh = out + (size_t)33554432;
    float* lrc = lrh + (size_t)2097152;
    float* lrg = lrc + (size_t)2097152;

    char* ws = (char*)d_ws;
    u16* convx = (u16*)ws;                            // 35,651,584 B
    size_t off = 35651584 + 4096;
    u16* cT_a = (u16*)(ws + off); off += 2230272;
    u16* cT_b = (u16*)(ws + off); off += 2230272;
    u16* XT = (u16*)(ws + off); off += 53526528;      // 32*4356*192*2
    u16* Wr = (u16*)(ws + off);                       // 1,566,720 B

    static const int offs[4] = {0, 92160, 230400, 460800};

    zero_border<<<dim3(780), 256, 0, stream>>>(XT);
    hipMemsetAsync(cT_a, 0, 2230272, stream);         // halos must stay 0
    hipMemsetAsync(cT_b, 0, 2230272, stream);
    transpose_halo<<<dim3(16, 1, 32), 256, 0, stream>>>(x, XT, 32);

    WP wp;
    for (int l = 0; l < 4; ++l) {
        wp.p[l * 2]     = (const float*)d_in[1 + 4 * l];
        wp.p[l * 2 + 1] = (const float*)d_in[3 + 4 * l];
    }
    prep_w_all<<<dim3((783360 + 255) / 256), 256, 0, stream>>>(wp, Wr);

    for (int l = 0; l < 4; ++l) {
        const float* bf = (const float*)d_in[2 + 4 * l];
        const float* bb = (const float*)d_in[4 + 4 * l];
        int cin = (l == 0) ? 32 : 64 * l;
        int ci_total = cin + 32;
        const u16* Wrl = Wr + offs[l];

        convx_mfma<<<dim3(32, 1, 16), 512, 0, stream>>>(XT, Wrl, bf, bb, convx, cin, ci_total);

        for (int s = 0; s < 8; ++s) {
            const u16* cin_p = (s & 1) ? cT_b : cT_a;
            u16* cout_p      = (s & 1) ? cT_a : cT_b;
            rec_mfma<<<dim3(8, 1, 32), 512, 0, stream>>>(
                cin_p, cout_p, Wrl, convx, out, lrh, lrc, lrg, XT,
                cin, ci_total, l, s);
        }
    }
}

// Round 19
// 558.536 us; speedup vs baseline: 1.2874x; 1.0042x over previous
//
#include <hip/hip_runtime.h>
#include <math.h>

#define T_STEPS 8
#define HW 4096
#define XSTR 192                    // XT channel stride (fixed, max cin)
#define FR_ROW 4352                 // convx u16 per (img,row)

typedef unsigned short u16;
typedef __attribute__((ext_vector_type(8))) short short8;
typedef __attribute__((ext_vector_type(4))) short short4v;
typedef __attribute__((ext_vector_type(4))) float f32x4;

__device__ __forceinline__ u16 f2bf(float f) {
    unsigned u = __builtin_bit_cast(unsigned, f);
    u += 0x7fffu + ((u >> 16) & 1u);
    return (u16)(u >> 16);
}
__device__ __forceinline__ float bf2f(u16 h) {
    unsigned u = ((unsigned)h) << 16;
    return __builtin_bit_cast(float, u);
}
__device__ __forceinline__ float ftanh(float x) {
    float e = __expf(2.f * x);
    return 1.f - 2.f * __builtin_amdgcn_rcpf(e + 1.f);
}
__device__ __forceinline__ float fsigm(float x) {
    return __builtin_amdgcn_rcpf(1.f + __expf(-x));
}
__device__ __forceinline__ void gload_lds16(const u16* g, u16* lds) {
    __builtin_amdgcn_global_load_lds(
        (const __attribute__((address_space(1))) unsigned*)g,
        (__attribute__((address_space(3))) unsigned*)lds, 16, 0, 0);
}

// ---------------------------------------------------------------------------
// l0 only: fp32 x [img][32][64][64] -> bf16 XT[img][66][66][192] ch 0..31
// ---------------------------------------------------------------------------
__global__ __launch_bounds__(256) void transpose_halo(
    const float* __restrict__ src, u16* __restrict__ XT, int src_ctot)
{
    __shared__ float tile[32][257];
    const int img = blockIdx.z;
    const int px0 = blockIdx.x * 256;
    const float* s = src + (size_t)img * src_ctot * HW + px0;
    #pragma unroll
    for (int c = 0; c < 32; ++c)
        tile[c][threadIdx.x] = s[(size_t)c * HW + threadIdx.x];
    __syncthreads();
    const int c = threadIdx.x & 31, pb = threadIdx.x >> 5;
    const int r0 = px0 >> 6;
    for (int p = pb; p < 256; p += 8) {
        int row = r0 + (p >> 6), col = p & 63;
        XT[((size_t)img * 4356 + (row + 1) * 66 + col + 1) * XSTR + c] = f2bf(tile[c][p]);
    }
}

// ---------------------------------------------------------------------------
// Zero only XT's halo border cells (260 px/img, all 192 ch)
// ---------------------------------------------------------------------------
__global__ __launch_bounds__(256) void zero_border(u16* __restrict__ XT)
{
    int idx = blockIdx.x * 256 + threadIdx.x;      // 32*260*24 = 199,680
    if (idx >= 199680) return;
    int c8 = idx % 24;
    int rest = idx / 24;
    int bp = rest % 260;
    int img = rest / 260;
    int row, col;
    if (bp < 66)       { row = 0;  col = bp; }
    else if (bp < 132) { row = 65; col = bp - 66; }
    else if (bp < 196) { col = 0;  row = 1 + bp - 132; }
    else               { col = 65; row = 1 + bp - 196; }
    short8 zz = {0, 0, 0, 0, 0, 0, 0, 0};
    *(short8*)(XT + ((size_t)img * 4356 + row * 66 + col) * XSTR + c8 * 8) = zz;
}

// ---------------------------------------------------------------------------
// Pack ALL layers' weights in one launch:
// Wr[l] at offs[l], layout [dir][tap][80][ci_total(l)] bf16 (co >= 65 zeroed)
// ---------------------------------------------------------------------------
struct WP { const float* p[8]; };   // wf0,wb0,wf1,wb1,wf2,wb2,wf3,wb3

__global__ __launch_bounds__(256) void prep_w_all(WP wp, u16* __restrict__ Wr)
{
    int idx = blockIdx.x * 256 + threadIdx.x;
    if (idx >= 783360) return;
    const int offs[5] = {0, 92160, 230400, 460800, 783360};
    const int cit[4]  = {64, 96, 160, 224};
    int lay = 0;
    while (idx >= offs[lay + 1]) ++lay;
    int li = idx - offs[lay];
    int ci_total = cit[lay];
    int ci = li % ci_total;
    int rest = li / ci_total;
    int co = rest % 80; rest /= 80;
    int tap = rest % 9;
    int dir = rest / 9;
    const float* w = wp.p[lay * 2 + dir];
    float v = (co < 65) ? w[((size_t)co * ci_total + ci) * 9 + tap] : 0.f;
    Wr[idx] = f2bf(v);
}

// ---------------------------------------------------------------------------
// MFMA x-conv (frozen geometry: 4 rows x 2 dirs, single 25KB LDS stage,
// XCD-pinned img). A/B change vs r18: staging via global_load_lds (16B) —
// no VGPR round-trip, no ds_writes; same barrier structure.
// ---------------------------------------------------------------------------
__global__ __launch_bounds__(512, 2) void convx_mfma(
    const u16* __restrict__ XT, const u16* __restrict__ Wr,
    const float* __restrict__ b_f, const float* __restrict__ b_b,
    u16* __restrict__ convx, int cin, int ci_total)
{
    __shared__ u16 xs[6 * 66 * 32];       // 25,344 B
    const int tid = threadIdx.x;
    const int l = tid & 63, wv = tid >> 6;   // 8 waves
    const int g = l >> 4, ln16 = l & 15;
    const int img = blockIdx.x;              // t*4 + b  (fast dim -> XCD-pinned)
    const int dir = wv & 1;
    const int wrow = wv >> 1;                // 0..3
    const int r0  = blockIdx.z * 4;
    const int orow = r0 + wrow;

    const float* bias = dir ? b_b : b_f;
    f32x4 acc[5][4];
    #pragma unroll
    for (int mt = 0; mt < 5; ++mt)
        #pragma unroll
        for (int r = 0; r < 4; ++r) {
            int co = mt * 16 + g * 4 + r;
            float bv = (co < 65) ? bias[co] : 0.f;
            #pragma unroll
            for (int nt = 0; nt < 4; ++nt) acc[mt][nt][r] = bv;
        }

    const u16* wdir = Wr + (size_t)dir * 9 * 80 * ci_total + g * 8;
    const u16* xim  = XT + (size_t)img * 4356 * XSTR;

    for (int ch = 0; ch < cin; ch += 32) {
        __syncthreads();
        // stage rows r0..r0+5, 66 px, 32 ch -> 1584 x 16B via global_load_lds
        // (LDS dest = idx*16: wave-uniform base + lane*16 — HW constraint OK)
        #pragma unroll
        for (int k = 0; k < 4; ++k) {
            int idx = k * 512 + tid;
            if (idx < 1584)
                gload_lds16(xim + (size_t)(r0 * 66 + (idx >> 2)) * XSTR + ch + (idx & 3) * 8,
                            xs + (size_t)idx * 8);
        }
        __syncthreads();

        #pragma unroll
        for (int ky = 0; ky < 3; ++ky) {
            #pragma unroll
            for (int kx = 0; kx < 3; ++kx) {
                const int tap = ky * 3 + kx;
                const u16* xb = xs + ((size_t)((wrow + ky) * 66 + ln16 + kx)) * 32 + g * 8;
                short8 bv0 = *(const short8*)(xb);
                short8 bv1 = *(const short8*)(xb + 16 * 32);
                short8 bv2 = *(const short8*)(xb + 32 * 32);
                short8 bv3 = *(const short8*)(xb + 48 * 32);
                const u16* wb_ = wdir + ((size_t)tap * 80 + ln16) * ci_total + ch;
                #pragma unroll
                for (int mt = 0; mt < 5; ++mt) {
                    short8 af = *(const short8*)(wb_ + (size_t)mt * 16 * ci_total);
                    acc[mt][0] = __builtin_amdgcn_mfma_f32_16x16x32_bf16(af, bv0, acc[mt][0], 0, 0, 0);
                    acc[mt][1] = __builtin_amdgcn_mfma_f32_16x16x32_bf16(af, bv1, acc[mt][1], 0, 0, 0);
                    acc[mt][2] = __builtin_amdgcn_mfma_f32_16x16x32_bf16(af, bv2, acc[mt][2], 0, 0, 0);
                    acc[mt][3] = __builtin_amdgcn_mfma_f32_16x16x32_bf16(af, bv3, acc[mt][3], 0, 0, 0);
                }
            }
        }
    }

    const int zimg = dir * 32 + img;
    u16* cb = convx + ((size_t)zimg * 64 + orow) * FR_ROW;
    #pragma unroll
    for (int mt = 0; mt < 4; ++mt)
        #pragma unroll
        for (int nt = 0; nt < 4; ++nt) {
            short4v pk;
            #pragma unroll
            for (int r = 0; r < 4; ++r) pk[r] = (short)f2bf(acc[mt][nt][r]);
            *(short4v*)(cb + (size_t)(nt * 4 + mt) * 256 + l * 4) = pk;
        }
    if (g == 0) {
        #pragma unroll
        for (int nt = 0; nt < 4; ++nt) {
            short4v pk;
            #pragma unroll
            for (int r = 0; r < 4; ++r) pk[r] = (short)f2bf(acc[4][nt][r]);
            *(short4v*)(cb + 4096 + nt * 64 + ln16 * 4) = pk;
        }
    }
}

// ---------------------------------------------------------------------------
// Recurrent step (r12/r15 version — unchanged): role-split, deferred
// convx-add, XCD-pinned z. 8 waves = (2 rows x 2 col-halves) x 2 roles.
// ---------------------------------------------------------------------------
__global__ __launch_bounds__(512) void rec_mfma(
    const u16* __restrict__ cT_in, u16* __restrict__ cT_out,
    const u16* __restrict__ Wr, const u16* __restrict__ convx,
    float* __restrict__ out_t,
    float* __restrict__ lrh, float* __restrict__ lrc, float* __restrict__ lrg,
    u16* __restrict__ XT,
    int cin, int ci_total, int layer, int step)
{
    const int tid = threadIdx.x;
    const int l = tid & 63, w = tid >> 6;
    const int g = l >> 4, ln16 = l & 15;
    const int role = w & 1, ws = w >> 1;
    const int z = blockIdx.x;                  // dir*4 + b (fast dim -> XCD-pinned)
    const int dir = z >> 2, b = z & 3;
    const int t = dir ? (7 - step) : step;
    const int row  = blockIdx.z * 2 + (ws >> 1);
    const int nb   = (ws & 1) * 2;
    const int col0 = nb * 16;
    const int zimg = dir * 32 + t * 4 + b;
    const int m0 = role * 2;                   // this role's first mt

    // issue convx fragment loads early (consumed only in the epilogue)
    const u16* cxb = convx + ((size_t)zimg * 64 + row) * FR_ROW;
    short4v cx[3][2];
    #pragma unroll
    for (int j = 0; j < 2; ++j)
        #pragma unroll
        for (int nt = 0; nt < 2; ++nt)
            cx[j][nt] = *(const short4v*)(cxb + (size_t)((nb + nt) * 4 + (m0 + j)) * 256 + l * 4);
    #pragma unroll
    for (int nt = 0; nt < 2; ++nt)
        cx[2][nt] = (g == 0)
            ? *(const short4v*)(cxb + 4096 + (nb + nt) * 64 + ln16 * 4)
            : (short4v){0, 0, 0, 0};

    f32x4 acc[3][2] = {};
    if (step > 0) {
        const u16* wdir = Wr + (size_t)dir * 9 * 80 * ci_total + cin + g * 8;
        const u16* cim  = cT_in + (size_t)z * 4356 * 32 + g * 8;
        __builtin_amdgcn_s_setprio(1);
        #pragma unroll
        for (int ky = 0; ky < 3; ++ky) {
            #pragma unroll
            for (int kx = 0; kx < 3; ++kx) {
                const int tap = ky * 3 + kx;
                const u16* xb_ = cim + (size_t)((row + ky) * 66 + col0 + ln16 + kx) * 32;
                short8 bv0 = *(const short8*)(xb_);
                short8 bv1 = *(const short8*)(xb_ + 16 * 32);
                const u16* wb_ = wdir + ((size_t)tap * 80 + ln16) * ci_total;
                short8 af0 = *(const short8*)(wb_ + (size_t)(m0    ) * 16 * ci_total);
                short8 af1 = *(const short8*)(wb_ + (size_t)(m0 + 1) * 16 * ci_total);
                short8 af4 = *(const short8*)(wb_ + (size_t)4 * 16 * ci_total);
                acc[0][0] = __builtin_amdgcn_mfma_f32_16x16x32_bf16(af0, bv0, acc[0][0], 0, 0, 0);
                acc[0][1] = __builtin_amdgcn_mfma_f32_16x16x32_bf16(af0, bv1, acc[0][1], 0, 0, 0);
                acc[1][0] = __builtin_amdgcn_mfma_f32_16x16x32_bf16(af1, bv0, acc[1][0], 0, 0, 0);
                acc[1][1] = __builtin_amdgcn_mfma_f32_16x16x32_bf16(af1, bv1, acc[1][1], 0, 0, 0);
                acc[2][0] = __builtin_amdgcn_mfma_f32_16x16x32_bf16(af4, bv0, acc[2][0], 0, 0, 0);
                acc[2][1] = __builtin_amdgcn_mfma_f32_16x16x32_bf16(af4, bv1, acc[2][1], 0, 0, 0);
            }
        }
        __builtin_amdgcn_s_setprio(0);
    }

    const bool last_f = (dir == 0) && (step == 7);
    float val[2], gv[2];
    #pragma unroll
    for (int nt = 0; nt < 2; ++nt) {
        val[nt] = fsigm(ftanh(acc[2][nt][0] + bf2f((u16)cx[2][nt][0])));
        gv[nt]  = __shfl(val[nt], ln16);       // broadcast from g==0 lanes
    }

    if (role == 0) {
        // h epilogue: acc[j] is mt j -> co = j*16 + g*4 + r
        const size_t obase = (size_t)(t * 4 + b) * 256 + 64 * layer + dir * 32;
        const int chb = 64 * layer + dir * 32;
        #pragma unroll
        for (int j = 0; j < 2; ++j)
            #pragma unroll
            for (int nt = 0; nt < 2; ++nt) {
                int px = row * 64 + col0 + nt * 16 + ln16;
                short4v pkh;
                #pragma unroll
                for (int r = 0; r < 4; ++r) {
                    int co = j * 16 + g * 4 + r;
                    float v = ftanh(acc[j][nt][r] + bf2f((u16)cx[j][nt][r]));
                    out_t[(obase + co) * HW + px] = v;
                    pkh[r] = (short)f2bf(v);
                    if (last_f) lrh[((size_t)(layer * 4 + b) * 32 + co) * HW + px] = v;
                }
                if (layer < 3)
                    *(short4v*)(XT + ((size_t)(t * 4 + b) * 4356 + (row + 1) * 66 +
                                      (col0 + nt * 16 + ln16 + 1)) * XSTR + chb + j * 16 + g * 4) = pkh;
            }
        if (last_f && g == 0) {
            #pragma unroll
            for (int nt = 0; nt < 2; ++nt)
                lrg[(size_t)(layer * 4 + b) * HW + row * 64 + col0 + nt * 16 + ln16] = val[nt];
        }
    } else {
        // c epilogue: acc[j] is mt 2+j -> k = j*16 + g*4 + r
        #pragma unroll
        for (int j = 0; j < 2; ++j)
            #pragma unroll
            for (int nt = 0; nt < 2; ++nt) {
                short4v pk;
                #pragma unroll
                for (int r = 0; r < 4; ++r) {
                    int k = j * 16 + g * 4 + r;
                    float c = gv[nt] * ftanh(acc[j][nt][r] + bf2f((u16)cx[j][nt][r]));
                    pk[r] = (short)f2bf(c);
                    if (last_f)
                        lrc[((size_t)(layer * 4 + b) * 32 + k) * HW + row * 64 + col0 + nt * 16 + ln16] = c;
                }
                if (step < 7) {
                    int colh = col0 + nt * 16 + ln16 + 1;
                    *(short4v*)(cT_out + ((size_t)z * 4356 + (row + 1) * 66 + colh) * 32 + j * 16 + g * 4) = pk;
                }
            }
    }
}

extern "C" void kernel_launch(void* const* d_in, const int* in_sizes, int n_in,
                              void* d_out, int out_size, void* d_ws, size_t ws_size,
                              hipStream_t stream)
{
    const float* x = (const float*)d_in[0];
    float* out = (float*)d_out;                       // (8,4,256,64,64)
    float* lrh = out + (size_t)33554432;
    float* lrc = lrh + (size_t)2097152;
    float* lrg = lrc + (size_t)2097152;

    char* ws = (char*)d_ws;
    u16* convx = (u16*)ws;                            // 35,651,584 B
    size_t off = 35651584 + 4096;
    u16* cT_a = (u16*)(ws + off); off += 2230272;
    u16* cT_b = (u16*)(ws + off); off += 2230272;
    u16* XT = (u16*)(ws + off); off += 53526528;      // 32*4356*192*2
    u16* Wr = (u16*)(ws + off);                       // 1,566,720 B

    static const int offs[4] = {0, 92160, 230400, 460800};

    zero_border<<<dim3(780), 256, 0, stream>>>(XT);
    hipMemsetAsync(cT_a, 0, 2230272, stream);         // halos must stay 0
    hipMemsetAsync(cT_b, 0, 2230272, stream);
    transpose_halo<<<dim3(16, 1, 32), 256, 0, stream>>>(x, XT, 32);

    WP wp;
    for (int l = 0; l < 4; ++l) {
        wp.p[l * 2]     = (const float*)d_in[1 + 4 * l];
        wp.p[l * 2 + 1] = (const float*)d_in[3 + 4 * l];
    }
    prep_w_all<<<dim3((783360 + 255) / 256), 256, 0, stream>>>(wp, Wr);

    for (int l = 0; l < 4; ++l) {
        const float* bf = (const float*)d_in[2 + 4 * l];
        const float* bb = (const float*)d_in[4 + 4 * l];
        int cin = (l == 0) ? 32 : 64 * l;
        int ci_total = cin + 32;
        const u16* Wrl = Wr + offs[l];

        convx_mfma<<<dim3(32, 1, 16), 512, 0, stream>>>(XT, Wrl, bf, bb, convx, cin, ci_total);

        for (int s = 0; s < 8; ++s) {
            const u16* cin_p = (s & 1) ? cT_b : cT_a;
            u16* cout_p      = (s & 1) ? cT_a : cT_b;
            rec_mfma<<<dim3(8, 1, 32), 512, 0, stream>>>(
                cin_p, cout_p, Wrl, convx, out, lrh, lrc, lrg, XT,
                cin, ci_total, l, s);
        }
    }
}